// Round 2
// baseline (685.733 us; speedup 1.0000x reference)
//
#include <hip/hip_runtime.h>

// out[b,d,m] = (sum_n seg[b,d,n]*Wt[b,m,n]) / (sum_n Wt[b,m,n]),  Wt = W*(W>0.85)
// bs=4, d=16, n=4096. W = 268 MB read once -> memory-bound, floor ~43 us.
// One wave handles 4 rows (m); lanes stride n with float4; W is register
// double-buffered (prefetch chunk c+1 before computing chunk c). Epilogue is a
// recursive-halving scatter-reduce: lane l ends owning output bitrev6(l), so
// all 64 lanes issue one coalescible store.

#define N_DIM 4096
#define D_DIM 16
#define THRESH 0.85f
#define RPW 4          // rows per wave
#define CHUNK 256      // n elements per chunk (64 lanes x float4)

__global__ __launch_bounds__(256, 4) void regu_kernel(
    const float* __restrict__ seg,   // [4][16][4096]
    const float* __restrict__ W,     // [4][4096][4096]
    float* __restrict__ out)         // [4][16][4096]
{
    const int lane = threadIdx.x & 63;
    const int wave_in_block = threadIdx.x >> 6;
    const int gwave = blockIdx.x * 4 + wave_in_block;   // 4096 waves
    const int row_base = gwave * RPW;                   // [0, 16384)
    const int b  = row_base >> 12;
    const int m0 = row_base & (N_DIM - 1);

    const float* Wp   = W   + ((size_t)b * N_DIM + m0) * N_DIM + lane * 4;
    const float* segp = seg + (size_t)b * D_DIM * N_DIM + lane * 4;

    float vals[64];                 // vals[r*16+d] = acc for (row r, depth d)
    float rowsum[RPW];
#pragma unroll
    for (int i = 0; i < 64; ++i) vals[i] = 0.0f;
#pragma unroll
    for (int r = 0; r < RPW; ++r) rowsum[r] = 0.0f;

    float4 wbuf0[RPW], wbuf1[RPW];

    // preload chunk 0
#pragma unroll
    for (int r = 0; r < RPW; ++r)
        wbuf0[r] = *(const float4*)(Wp + (size_t)r * N_DIM);

    // one chunk: threshold wsrc, accumulate rowsum + FMAs against seg
    auto compute = [&](const float4* wsrc, int c) {
        float4 w4[RPW];
#pragma unroll
        for (int r = 0; r < RPW; ++r) {
            float4 v = wsrc[r];
            v.x = (v.x > THRESH) ? v.x : 0.0f;
            v.y = (v.y > THRESH) ? v.y : 0.0f;
            v.z = (v.z > THRESH) ? v.z : 0.0f;
            v.w = (v.w > THRESH) ? v.w : 0.0f;
            w4[r] = v;
            rowsum[r] += (v.x + v.y) + (v.z + v.w);
        }
        const float* sp = segp + c * CHUNK;
#pragma unroll
        for (int d = 0; d < D_DIM; ++d) {
            const float4 s = *(const float4*)(sp + d * N_DIM);
#pragma unroll
            for (int r = 0; r < RPW; ++r) {
                vals[r * D_DIM + d] += w4[r].x * s.x;
                vals[r * D_DIM + d] += w4[r].y * s.y;
                vals[r * D_DIM + d] += w4[r].z * s.z;
                vals[r * D_DIM + d] += w4[r].w * s.w;
            }
        }
    };

    for (int c = 0; c < N_DIM / CHUNK; c += 2) {
        // prefetch chunk c+1 into wbuf1, compute chunk c from wbuf0
        {
            const float* p = Wp + (size_t)(c + 1) * CHUNK;
#pragma unroll
            for (int r = 0; r < RPW; ++r)
                wbuf1[r] = *(const float4*)(p + (size_t)r * N_DIM);
        }
        compute(wbuf0, c);

        // prefetch chunk c+2 into wbuf0 (if any), compute chunk c+1 from wbuf1
        if (c + 2 < N_DIM / CHUNK) {
            const float* p = Wp + (size_t)(c + 2) * CHUNK;
#pragma unroll
            for (int r = 0; r < RPW; ++r)
                wbuf0[r] = *(const float4*)(p + (size_t)r * N_DIM);
        }
        compute(wbuf1, c + 1);
    }

    // ---- scatter-reduce: 64 partial sums -> one total per lane ----
    // After step k, each lane keeps S=32>>k entries; lane bit k picks which
    // half it keeps. Final: lane l holds total for index bitrev6(l).
#pragma unroll
    for (int k = 0; k < 6; ++k) {
        const int S = 32 >> k;
        const bool up = (lane >> k) & 1;
#pragma unroll
        for (int j = 0; j < S; ++j) {
            const float mine = up ? vals[j + S] : vals[j];
            const float send = up ? vals[j] : vals[j + S];
            vals[j] = mine + __shfl_xor(send, 1 << k, 64);
        }
    }

    // rowsums: classic butterfly, every lane ends with all 4 totals
#pragma unroll
    for (int r = 0; r < RPW; ++r) {
        float s = rowsum[r];
#pragma unroll
        for (int off = 1; off < 64; off <<= 1) s += __shfl_xor(s, off, 64);
        rowsum[r] = s;
    }

    // lane l owns output index j = bitrev6(l): r = j>>4, d = j&15
    const int j = __brev((unsigned)lane) >> 26;
    const int r = j >> 4;
    const int d = j & 15;
    const float inv = 1.0f / (r < 2 ? (r == 0 ? rowsum[0] : rowsum[1])
                                    : (r == 2 ? rowsum[2] : rowsum[3]));
    out[((size_t)b * D_DIM + d) * N_DIM + (m0 + r)] = vals[0] * inv;
}

extern "C" void kernel_launch(void* const* d_in, const int* in_sizes, int n_in,
                              void* d_out, int out_size, void* d_ws, size_t ws_size,
                              hipStream_t stream) {
    const float* seg = (const float*)d_in[0];   // [4,16,64,64] fp32
    const float* W   = (const float*)d_in[1];   // [4,4096,4096] fp32
    float* out = (float*)d_out;                 // [4,16,64,64] fp32

    regu_kernel<<<1024, 256, 0, stream>>>(seg, W, out);
}

// Round 3
// 405.003 us; speedup vs baseline: 1.6932x; 1.6932x over previous
//
#include <hip/hip_runtime.h>

// out[b,d,m] = (sum_n seg[b,d,n]*Wt[b,m,n]) / (sum_n Wt[b,m,n]),  Wt = W*(W>0.85)
// bs=4, d=16, n=4096. W = 268 MB read once -> memory-bound, floor ~43 us.
// R3: RPW=2 rows/wave to fit ~64 VGPRs (R2's RPW=4 + dbuf spilled: 854 MB
// scratch writes). Register double-buffer on W, nontemporal W loads,
// 8192 waves (2048 blocks) for latency hiding. No launch_bounds min-waves --
// that pushed the compiler to a 64-VGPR occupancy target and spilled.

typedef float v4f __attribute__((ext_vector_type(4)));

#define N_DIM 4096
#define D_DIM 16
#define THRESH 0.85f
#define RPW 2
#define CHUNK 256              // 64 lanes x float4
#define NCHUNK (N_DIM / CHUNK) // 16

__global__ __launch_bounds__(256) void regu_kernel(
    const float* __restrict__ seg,   // [4][16][4096]
    const float* __restrict__ W,     // [4][4096][4096]
    float* __restrict__ out)         // [4][16][4096]
{
    const int lane = threadIdx.x & 63;
    const int wv   = threadIdx.x >> 6;
    const int gwave = blockIdx.x * 4 + wv;     // 8192 waves
    const int row0  = gwave * RPW;             // [0, 16384)
    const int b  = row0 >> 12;
    const int m0 = row0 & (N_DIM - 1);

    const float* Wp   = W   + ((size_t)b * N_DIM + m0) * N_DIM + lane * 4;
    const float* segp = seg + (size_t)b * D_DIM * N_DIM + lane * 4;

    float acc[RPW * D_DIM];          // acc[r*16+d]
    float rowsum[RPW] = {0.f, 0.f};
#pragma unroll
    for (int i = 0; i < RPW * D_DIM; ++i) acc[i] = 0.f;

    v4f buf0[RPW], buf1[RPW];
#pragma unroll
    for (int r = 0; r < RPW; ++r)
        buf0[r] = __builtin_nontemporal_load((const v4f*)(Wp + (size_t)r * N_DIM));

    auto compute = [&](const v4f* wb, int c) {
        v4f w[RPW];
#pragma unroll
        for (int r = 0; r < RPW; ++r) {
            v4f v = wb[r];
            v.x = (v.x > THRESH) ? v.x : 0.f;
            v.y = (v.y > THRESH) ? v.y : 0.f;
            v.z = (v.z > THRESH) ? v.z : 0.f;
            v.w = (v.w > THRESH) ? v.w : 0.f;
            w[r] = v;
            rowsum[r] += (v.x + v.y) + (v.z + v.w);
        }
        const float* sp = segp + c * CHUNK;
#pragma unroll
        for (int d = 0; d < D_DIM; ++d) {
            const v4f s = *(const v4f*)(sp + d * N_DIM);
#pragma unroll
            for (int r = 0; r < RPW; ++r) {
                acc[r * D_DIM + d] += w[r].x * s.x;
                acc[r * D_DIM + d] += w[r].y * s.y;
                acc[r * D_DIM + d] += w[r].z * s.z;
                acc[r * D_DIM + d] += w[r].w * s.w;
            }
        }
    };

    for (int c = 0; c < NCHUNK; c += 2) {
        {
            const float* p = Wp + (size_t)(c + 1) * CHUNK;
#pragma unroll
            for (int r = 0; r < RPW; ++r)
                buf1[r] = __builtin_nontemporal_load((const v4f*)(p + (size_t)r * N_DIM));
        }
        compute(buf0, c);

        if (c + 2 < NCHUNK) {
            const float* p = Wp + (size_t)(c + 2) * CHUNK;
#pragma unroll
            for (int r = 0; r < RPW; ++r)
                buf0[r] = __builtin_nontemporal_load((const v4f*)(p + (size_t)r * N_DIM));
        }
        compute(buf1, c + 1);
    }

    // scatter-reduce: 32 partials over lane bits 0..4; after 5 steps lane l
    // (and l+32) hold the half-total for index j = bitrev5(l&31); one
    // cross-half add completes it.
#pragma unroll
    for (int k = 0; k < 5; ++k) {
        const int S = 16 >> k;
        const bool up = (lane >> k) & 1;
#pragma unroll
        for (int j = 0; j < S; ++j) {
            const float mine = up ? acc[j + S] : acc[j];
            const float send = up ? acc[j] : acc[j + S];
            acc[j] = mine + __shfl_xor(send, 1 << k, 64);
        }
    }
    acc[0] += __shfl_xor(acc[0], 32, 64);

#pragma unroll
    for (int r = 0; r < RPW; ++r) {
        float s = rowsum[r];
#pragma unroll
        for (int off = 1; off < 64; off <<= 1) s += __shfl_xor(s, off, 64);
        rowsum[r] = s;
    }

    if (lane < 32) {
        const int j = __brev((unsigned)lane) >> 27;   // bitrev5
        const int r = j >> 4;
        const int d = j & 15;
        const float inv = 1.0f / (r ? rowsum[1] : rowsum[0]);
        out[((size_t)b * D_DIM + d) * N_DIM + (m0 + r)] = acc[0] * inv;
    }
}

extern "C" void kernel_launch(void* const* d_in, const int* in_sizes, int n_in,
                              void* d_out, int out_size, void* d_ws, size_t ws_size,
                              hipStream_t stream) {
    const float* seg = (const float*)d_in[0];   // [4,16,64,64] fp32
    const float* W   = (const float*)d_in[1];   // [4,4096,4096] fp32
    float* out = (float*)d_out;                 // [4,16,64,64] fp32

    // 16384 rows / (2 rows/wave * 4 waves/block) = 2048 blocks
    regu_kernel<<<2048, 256, 0, stream>>>(seg, W, out);
}

// Round 4
// 354.327 us; speedup vs baseline: 1.9353x; 1.1430x over previous
//
#include <hip/hip_runtime.h>
#include <stdint.h>

// out[b,d,m] = (sum_n seg[b,d,n]*Wt[b,m,n]) / (sum_n Wt[b,m,n]),  Wt = W*(W>0.85)
// bs=4, d=16, n=4096. W = 268 MB read once -> memory floor ~43 us kernel.
// R4: seg staged in LDS (double-buffered, global_load_lds w=16) so the seg
// stream is on lgkmcnt, decoupled from the W vmcnt stream (in-order vmcnt
// entanglement was R3's stall). RPW=4 (R3's RPW=2 doubled seg amplification
// and regressed: kernel ~150us vs R1 ~128us). W loads nontemporal.

typedef float v4f __attribute__((ext_vector_type(4)));

#define N_DIM 4096
#define D_DIM 16
#define THRESH 0.85f
#define RPW 4                  // rows per wave; block = 4 waves = 16 rows
#define CHUNK 256              // n per chunk (64 lanes x float4)
#define NCHUNK (N_DIM / CHUNK) // 16

__global__ __launch_bounds__(256) void regu_kernel(
    const float* __restrict__ seg,   // [4][16][4096]
    const float* __restrict__ W,     // [4][4096][4096]
    float* __restrict__ out)         // [4][16][4096]
{
    __shared__ float stile[2][D_DIM * CHUNK];   // 2 x 16 KB seg tiles

    const int lane = threadIdx.x & 63;
    const int wv   = threadIdx.x >> 6;
    const int row0 = blockIdx.x * 16 + wv * RPW;   // [0, 16384)
    const int b  = row0 >> 12;
    const int m0 = row0 & (N_DIM - 1);

    const float* Wp   = W   + ((size_t)b * N_DIM + m0) * N_DIM + lane * 4;
    const float* segb = seg + (size_t)b * D_DIM * N_DIM;

    float acc[RPW * D_DIM];                 // acc[r*16+d]
    float rowsum[RPW] = {0.f, 0.f, 0.f, 0.f};
#pragma unroll
    for (int i = 0; i < RPW * D_DIM; ++i) acc[i] = 0.f;

    // stage chunk c of seg (16 rows x 1 KB) into stile[sb]; wave wv does rows
    // wv*4..wv*4+3. LDS dest is the wave-uniform row base (HW adds lane*16).
#define STAGE(c, sb)                                                          \
    do {                                                                      \
        _Pragma("unroll")                                                     \
        for (int j = 0; j < 4; ++j) {                                         \
            const int d_ = wv * 4 + j;                                        \
            const float* g_ = segb + (size_t)d_ * N_DIM + (c) * CHUNK + lane * 4; \
            __builtin_amdgcn_global_load_lds(                                 \
                (const __attribute__((address_space(1))) uint32_t*)g_,        \
                (__attribute__((address_space(3))) uint32_t*)&stile[sb][d_ * CHUNK], \
                16, 0, 0);                                                    \
        }                                                                     \
    } while (0)

    v4f wA[RPW], wB[RPW];

    // prologue: stage seg chunk 0, load W chunk 0
    STAGE(0, 0);
#pragma unroll
    for (int r = 0; r < RPW; ++r)
        wA[r] = __builtin_nontemporal_load((const v4f*)(Wp + (size_t)r * N_DIM));
    __syncthreads();   // drains vmcnt: tile0 + wA ready

    // one chunk: threshold W regs, rowsum, FMA against LDS seg tile
    auto compute = [&](const v4f* w_in, int sb) {
        v4f w[RPW];
#pragma unroll
        for (int r = 0; r < RPW; ++r) {
            v4f v = w_in[r];
            v.x = (v.x > THRESH) ? v.x : 0.f;
            v.y = (v.y > THRESH) ? v.y : 0.f;
            v.z = (v.z > THRESH) ? v.z : 0.f;
            v.w = (v.w > THRESH) ? v.w : 0.f;
            w[r] = v;
            rowsum[r] += (v.x + v.y) + (v.z + v.w);
        }
#pragma unroll
        for (int d = 0; d < D_DIM; ++d) {
            const v4f s = *(const v4f*)&stile[sb][d * CHUNK + lane * 4];
#pragma unroll
            for (int r = 0; r < RPW; ++r) {
                acc[r * D_DIM + d] += w[r].x * s.x;
                acc[r * D_DIM + d] += w[r].y * s.y;
                acc[r * D_DIM + d] += w[r].z * s.z;
                acc[r * D_DIM + d] += w[r].w * s.w;
            }
        }
    };

    for (int c = 0; c < NCHUNK; c += 2) {
        // iter c (even): compute from stile[0]/wA; stage c+1 -> stile[1]/wB
        STAGE(c + 1, 1);
        {
            const float* p = Wp + (size_t)(c + 1) * CHUNK;
#pragma unroll
            for (int r = 0; r < RPW; ++r)
                wB[r] = __builtin_nontemporal_load((const v4f*)(p + (size_t)r * N_DIM));
        }
        compute(wA, 0);
        __syncthreads();   // tile1/wB ready; everyone done reading tile0

        // iter c+1 (odd): compute from stile[1]/wB; stage c+2 -> stile[0]/wA
        if (c + 2 < NCHUNK) {
            STAGE(c + 2, 0);
            const float* p = Wp + (size_t)(c + 2) * CHUNK;
#pragma unroll
            for (int r = 0; r < RPW; ++r)
                wA[r] = __builtin_nontemporal_load((const v4f*)(p + (size_t)r * N_DIM));
        }
        compute(wB, 1);
        __syncthreads();
    }

    // scatter-reduce 64 partials: after 6 steps lane l holds the total for
    // index j = bitrev6(l)  (verified numerically in R2/R3)
#pragma unroll
    for (int k = 0; k < 6; ++k) {
        const int S = 32 >> k;
        const bool up = (lane >> k) & 1;
#pragma unroll
        for (int j = 0; j < S; ++j) {
            const float mine = up ? acc[j + S] : acc[j];
            const float send = up ? acc[j] : acc[j + S];
            acc[j] = mine + __shfl_xor(send, 1 << k, 64);
        }
    }

#pragma unroll
    for (int r = 0; r < RPW; ++r) {
        float s = rowsum[r];
#pragma unroll
        for (int off = 1; off < 64; off <<= 1) s += __shfl_xor(s, off, 64);
        rowsum[r] = s;
    }

    const int j = __brev((unsigned)lane) >> 26;   // bitrev6
    const int r = j >> 4;
    const int d = j & 15;
    const float inv = 1.0f / (r < 2 ? (r == 0 ? rowsum[0] : rowsum[1])
                                    : (r == 2 ? rowsum[2] : rowsum[3]));
    out[((size_t)b * D_DIM + d) * N_DIM + (m0 + r)] = acc[0] * inv;
}

extern "C" void kernel_launch(void* const* d_in, const int* in_sizes, int n_in,
                              void* d_out, int out_size, void* d_ws, size_t ws_size,
                              hipStream_t stream) {
    const float* seg = (const float*)d_in[0];   // [4,16,64,64] fp32
    const float* W   = (const float*)d_in[1];   // [4,4096,4096] fp32
    float* out = (float*)d_out;                 // [4,16,64,64] fp32

    // 16384 rows / (4 waves x 4 rows) = 1024 blocks
    regu_kernel<<<1024, 256, 0, stream>>>(seg, W, out);
}